// Round 1
// 175.508 us; speedup vs baseline: 1.0159x; 1.0159x over previous
//
#include <hip/hip_runtime.h>
#include <hip/hip_bf16.h>

constexpr int NB  = 2;
constexpr int SL  = 2048;
constexpr int EMB = 1024;
constexpr int NH  = 16;
constexpr int HD  = 64;
constexpr int MT  = NB * SL;               // 4096 rows for projection GEMMs
constexpr size_t PROJ = (size_t)MT * EMB;  // 4M elements per [N,L,E] buffer

typedef __attribute__((ext_vector_type(8))) short bf16x8;  // 8 bf16 (4 VGPRs)
typedef __attribute__((ext_vector_type(4))) float f32x4;   // MFMA C/D frag

__device__ inline short f2b(float f) {
  __hip_bfloat16 b = __float2bfloat16(f);
  short s; __builtin_memcpy(&s, &b, 2); return s;
}

#define GLDS16(g, l)                                                     \
  __builtin_amdgcn_global_load_lds(                                      \
      (const __attribute__((address_space(1))) void*)(g),                \
      (__attribute__((address_space(3))) void*)(l), 16, 0, 0)

// ---------------------------------------------------------------------------
// Cast fp32 -> bf16: x -> xb, {Wq,Wk,Wv} -> wqkv (concat rows), Wo -> wob.
// ---------------------------------------------------------------------------
__global__ __launch_bounds__(256) void cast_all(
    const float* __restrict__ x,  const float* __restrict__ wq,
    const float* __restrict__ wk, const float* __restrict__ wv,
    const float* __restrict__ wo, short* __restrict__ xb,
    short* __restrict__ wqkv, short* __restrict__ wob) {
  const size_t t = (size_t)blockIdx.x * 256 + threadIdx.x;  // float4 index
  const float* src; short* dst; size_t base;
  if (t < 1048576)      { src = x;  dst = xb;              base = 0; }
  else if (t < 1310720) { src = wq; dst = wqkv;            base = 1048576; }
  else if (t < 1572864) { src = wk; dst = wqkv + (1 << 20); base = 1310720; }
  else if (t < 1835008) { src = wv; dst = wqkv + (2 << 20); base = 1572864; }
  else                  { src = wo; dst = wob;             base = 1835008; }
  const size_t i = t - base;
  const float4 v = ((const float4*)src)[i];
  const short4 o = {f2b(v.x), f2b(v.y), f2b(v.z), f2b(v.w)};
  ((short4*)dst)[i] = o;
}

// ---------------------------------------------------------------------------
// QKV GEMM (m97 recipe): C = x[4096][1024] @ wqkv[3072][1024]^T.
// 128x128 tile, BK=32, global_load_lds w16. Epilogue per n-region:
//   0 -> Q * (log2e/32)  (exp2 + score-scale folded), row-major [seq][1024]
//   1 -> K fragment-blocked: Kp[nb][h][seq16][ks][G][lb][8]
//        element = K[seq16*16+lb][32ks+8G+j]; one 64-lane dwordx4 load in
//        attn (chunk = lane) covers one MFMA A-frag, fully coalesced.
//   2 -> V fragment-blocked: Vp[nb][h][kb32][mtd][g][lbv][8]
//        element = V^T[16mtd+lbv][32kb32 + pi(8g+j)], pi(8g+4hi+lo) =
//        16hi+4g+lo (PV B-operand key order). Same direct-load property.
// ---------------------------------------------------------------------------
__global__ __launch_bounds__(256) void gemm_qkv(
    const short* __restrict__ A, const short* __restrict__ W,
    short* __restrict__ qb, short* __restrict__ kb, short* __restrict__ vt) {
  __shared__ short As[128 * 32];
  __shared__ short Bs[128 * 32];
  const int tid = threadIdx.x;
  const int w = tid >> 6, lane = tid & 63;
  const int la = lane >> 4, lb = lane & 15;
  const int wm = w & 1, wn = w >> 1;
  const int m0 = blockIdx.y << 7, n0 = blockIdx.x << 7;
  const int srow = lane >> 2, scol = (lane & 3) << 3;
  const short* a0 = A + (size_t)(m0 + w * 16 + srow) * 1024 + scol;
  const short* b0 = W + (size_t)(n0 + w * 16 + srow) * 1024 + scol;
  short* lA0 = As + (w * 16) * 32;
  short* lA1 = As + (64 + w * 16) * 32;
  short* lB0 = Bs + (w * 16) * 32;
  short* lB1 = Bs + (64 + w * 16) * 32;

  f32x4 acc[4][4];
#pragma unroll
  for (int i = 0; i < 4; ++i)
#pragma unroll
    for (int j = 0; j < 4; ++j) acc[i][j] = (f32x4){0.f, 0.f, 0.f, 0.f};

  for (int k0 = 0; k0 < 1024; k0 += 32) {
    __syncthreads();
    GLDS16(a0 + k0, lA0);
    GLDS16(a0 + 64 * 1024 + k0, lA1);
    GLDS16(b0 + k0, lB0);
    GLDS16(b0 + 64 * 1024 + k0, lB1);
    __syncthreads();
    bf16x8 af[4], bfr[4];
#pragma unroll
    for (int i = 0; i < 4; ++i)
      af[i] = *(const bf16x8*)&As[(wm * 64 + i * 16 + lb) * 32 + la * 8];
#pragma unroll
    for (int j = 0; j < 4; ++j)
      bfr[j] = *(const bf16x8*)&Bs[(wn * 64 + j * 16 + lb) * 32 + la * 8];
#pragma unroll
    for (int i = 0; i < 4; ++i)
#pragma unroll
      for (int j = 0; j < 4; ++j)
        acc[i][j] = __builtin_amdgcn_mfma_f32_16x16x32_bf16(af[i], bfr[j],
                                                            acc[i][j], 0, 0, 0);
  }

  const int region = n0 >> 10;  // block-uniform (n-tile 128 < 1024)
  if (region == 0) {
    const float sc = 0.03125f * 1.44269504f;  // 1/sqrt(1024) * log2(e)
#pragma unroll
    for (int j = 0; j < 4; ++j) {
      const int nj = (n0 & 1023) + wn * 64 + j * 16 + lb;
#pragma unroll
      for (int i = 0; i < 4; ++i) {
        const int mi = m0 + wm * 64 + i * 16 + la * 4;
#pragma unroll
        for (int r = 0; r < 4; ++r)
          qb[(size_t)(mi + r) * 1024 + nj] = f2b(acc[i][j][r] * sc);
      }
    }
  } else if (region == 1) {
    // K fragment-blocked
#pragma unroll
    for (int j = 0; j < 4; ++j) {
      const int nj = (n0 & 1023) + wn * 64 + j * 16 + lb;
      const int hh = nj >> 6, d = nj & 63;
      const int ks = d >> 5, Gd = (d >> 3) & 3, jj = d & 7;
#pragma unroll
      for (int i = 0; i < 4; ++i) {
        const int mi = m0 + wm * 64 + i * 16 + la * 4;
        const int nbi = mi >> 11, seq = mi & (SL - 1);
        const size_t base = ((size_t)(nbi * NH + hh) << 17) +
                            (size_t)(seq >> 4) * 1024 + ks * 512 + Gd * 128 +
                            (seq & 15) * 8 + jj;
#pragma unroll
        for (int r = 0; r < 4; ++r) kb[base + r * 8] = f2b(acc[i][j][r]);
      }
    }
  } else {
    // V fragment-blocked (PV key-permutation folded in)
#pragma unroll
    for (int j = 0; j < 4; ++j) {
      const int nv = (n0 - 2048) + wn * 64 + j * 16 + lb;
      const int hh = nv >> 6, d = nv & 63;
      const int mtd = d >> 4, lbv = d & 15;
#pragma unroll
      for (int i = 0; i < 4; ++i) {
        const int mi = m0 + wm * 64 + i * 16 + la * 4;
        const int nbi = mi >> 11, seq = mi & (SL - 1);
        const int kq = seq >> 5, g = (seq >> 2) & 3, hi = (seq >> 4) & 1;
        const short4 o = {f2b(acc[i][j][0]), f2b(acc[i][j][1]),
                          f2b(acc[i][j][2]), f2b(acc[i][j][3])};
        *(short4*)&vt[((size_t)(nbi * NH + hh) << 17) + (size_t)kq * 2048 +
                      mtd * 512 + g * 128 + lbv * 8 + 4 * hi] = o;
      }
    }
  }
}

// ---------------------------------------------------------------------------
// Out GEMM: out = ab[4096][1024](bf16) @ wob[1024][1024]^T + bias, fp32 out.
// ---------------------------------------------------------------------------
__global__ __launch_bounds__(256) void gemm_out(
    const short* __restrict__ A, const short* __restrict__ W,
    const float* __restrict__ bias, float* __restrict__ out) {
  __shared__ short As[128 * 32];
  __shared__ short Bs[64 * 32];
  const int tid = threadIdx.x;
  const int w = tid >> 6, lane = tid & 63;
  const int la = lane >> 4, lb = lane & 15;
  const int wm = w & 1, wn = w >> 1;
  const int m0 = blockIdx.y << 7, n0 = blockIdx.x << 6;
  const int srow = lane >> 2, scol = (lane & 3) << 3;
  const short* a0 = A + (size_t)(m0 + w * 16 + srow) * 1024 + scol;
  const short* b0 = W + (size_t)(n0 + w * 16 + srow) * 1024 + scol;
  short* lA0 = As + (w * 16) * 32;
  short* lA1 = As + (64 + w * 16) * 32;
  short* lB0 = Bs + (w * 16) * 32;

  f32x4 acc[4][2];
#pragma unroll
  for (int i = 0; i < 4; ++i)
#pragma unroll
    for (int j = 0; j < 2; ++j) acc[i][j] = (f32x4){0.f, 0.f, 0.f, 0.f};

  for (int k0 = 0; k0 < 1024; k0 += 32) {
    __syncthreads();
    GLDS16(a0 + k0, lA0);
    GLDS16(a0 + 64 * 1024 + k0, lA1);
    GLDS16(b0 + k0, lB0);
    __syncthreads();
    bf16x8 af[4], bfr[2];
#pragma unroll
    for (int i = 0; i < 4; ++i)
      af[i] = *(const bf16x8*)&As[(wm * 64 + i * 16 + lb) * 32 + la * 8];
#pragma unroll
    for (int j = 0; j < 2; ++j)
      bfr[j] = *(const bf16x8*)&Bs[(wn * 32 + j * 16 + lb) * 32 + la * 8];
#pragma unroll
    for (int i = 0; i < 4; ++i)
#pragma unroll
      for (int j = 0; j < 2; ++j)
        acc[i][j] = __builtin_amdgcn_mfma_f32_16x16x32_bf16(af[i], bfr[j],
                                                            acc[i][j], 0, 0, 0);
  }
#pragma unroll
  for (int j = 0; j < 2; ++j) {
    const int nj = n0 + wn * 32 + j * 16 + lb;
    const float bv = bias[nj];
#pragma unroll
    for (int i = 0; i < 4; ++i) {
      const int mi = m0 + wm * 64 + i * 16 + la * 4;
#pragma unroll
      for (int r = 0; r < 4; ++r)
        out[(size_t)(mi + r) * 1024 + nj] = acc[i][j][r] + bv;
    }
  }
}

// ---------------------------------------------------------------------------
// Flash attention v8: zero-LDS main loop, direct global->register K/V.
//  * gemm_qkv writes K and V in fragment-blocked layouts, so each MFMA
//    A-fragment is one fully-coalesced 64-lane dwordx4 load from L2 (per
//    (n,h) the 512 KB K+V slice is XCD-L2-resident; grid keeps the 16
//    qt-blocks of a slice on one XCD: id = h + 16*qt + 512*n).
//  * No barriers / no staging in the main loop: waves free-run, phase
//    decorrelation keeps the matrix pipe fed; LDS used only for the final
//    cross-wave O/l reduction (35 KB vs 72 KB before).
//  * Manual 2x unroll with static ping-pong register buffers (rule #20):
//    loads for sub-round t+1 issue a full compute phase (~500 cyc) before
//    use -> L2 latency (~250 cyc) hidden without extra waves.
//  * Per-wave key order identical to v7 -> bitwise-identical numerics.
// ---------------------------------------------------------------------------
#define LOADK(DK, KB32)                                                      \
  do {                                                                       \
    _Pragma("unroll") for (int rr_ = 0; rr_ < 2; ++rr_)                      \
        _Pragma("unroll") for (int ks_ = 0; ks_ < 2; ++ks_)                  \
            DK[rr_][ks_] = *(const bf16x8*)(Kb + (size_t)(KB32) * 2048 +     \
                                            rr_ * 1024 + ks_ * 512);         \
  } while (0)

#define LOADV(DV, KB32)                                                      \
  do {                                                                       \
    _Pragma("unroll") for (int md_ = 0; md_ < 4; ++md_)                      \
        DV[md_] = *(const bf16x8*)(Vb + (size_t)(KB32) * 2048 + md_ * 512);  \
  } while (0)

#define ATTN_STEP(AK, AV)                                                    \
  do {                                                                       \
    f32x4 S[2][4];                                                           \
    _Pragma("unroll") for (int mt = 0; mt < 2; ++mt)                         \
        _Pragma("unroll") for (int nt = 0; nt < 4; ++nt)                     \
            S[mt][nt] = (f32x4){0.f, 0.f, 0.f, 0.f};                         \
    _Pragma("unroll") for (int ks = 0; ks < 2; ++ks)                         \
        _Pragma("unroll") for (int nt = 0; nt < 4; ++nt) {                   \
      S[0][nt] = __builtin_amdgcn_mfma_f32_16x16x32_bf16(AK[0][ks],          \
                     bQ[nt][ks], S[0][nt], 0, 0, 0);                         \
      S[1][nt] = __builtin_amdgcn_mfma_f32_16x16x32_bf16(AK[1][ks],          \
                     bQ[nt][ks], S[1][nt], 0, 0, 0);                         \
    }                                                                        \
    _Pragma("unroll") for (int nt = 0; nt < 4; ++nt) {                       \
      _Pragma("unroll") for (int mt = 0; mt < 2; ++mt)                       \
          _Pragma("unroll") for (int r = 0; r < 4; ++r) {                    \
        const float p = __builtin_amdgcn_exp2f(S[mt][nt][r]);                \
        S[mt][nt][r] = p;                                                    \
        lacc[nt] += p;                                                       \
      }                                                                      \
      bf16x8 B2;                                                             \
      B2[0] = f2b(S[0][nt][0]); B2[1] = f2b(S[0][nt][1]);                    \
      B2[2] = f2b(S[0][nt][2]); B2[3] = f2b(S[0][nt][3]);                    \
      B2[4] = f2b(S[1][nt][0]); B2[5] = f2b(S[1][nt][1]);                    \
      B2[6] = f2b(S[1][nt][2]); B2[7] = f2b(S[1][nt][3]);                    \
      _Pragma("unroll") for (int mtd = 0; mtd < 4; ++mtd)                    \
          O[mtd][nt] = __builtin_amdgcn_mfma_f32_16x16x32_bf16(              \
              AV[mtd], B2, O[mtd][nt], 0, 0, 0);                             \
    }                                                                        \
  } while (0)

__global__ __launch_bounds__(256, 2) void attn_mfma(const short* __restrict__ Qg,
                                                    const short* __restrict__ Kp,
                                                    const short* __restrict__ Vp,
                                                    short* __restrict__ Ab) {
  __shared__ __align__(16) float red[2][64][68];  // 34816 B
  __shared__ float lred[128];
  const int tid = threadIdx.x;
  const int w = tid >> 6, lane = tid & 63;
  const int G = lane >> 4, lb = lane & 15;
  const int wk = w & 1, wq = w >> 1;
  const int h = blockIdx.x, qt = blockIdx.y, n = blockIdx.z;

  // ---- Q fragments: global -> regs, once. q = 64wq+16nt+lb, d = 32ks+8G
  const short* Qb = Qg + ((size_t)(n * SL + (qt << 7) + 64 * wq)) * EMB + h * HD;
  bf16x8 bQ[4][2];
#pragma unroll
  for (int nt = 0; nt < 4; ++nt)
#pragma unroll
    for (int ks = 0; ks < 2; ++ks)
      bQ[nt][ks] =
          *(const bf16x8*)(Qb + (size_t)(16 * nt + lb) * EMB + 32 * ks + 8 * G);

  f32x4 O[4][4];  // [mtd: d=16mtd+4G+r][nt: q=64wq+16nt+lb]
  float lacc[4] = {0.f, 0.f, 0.f, 0.f};
#pragma unroll
  for (int i = 0; i < 4; ++i)
#pragma unroll
    for (int j = 0; j < 4; ++j) O[i][j] = (f32x4){0.f, 0.f, 0.f, 0.f};

  // fragment-blocked bases; fold per-lane 16B chunk offset into the pointer
  const short* Kb = Kp + (((size_t)(n * NH + h)) << 17) + lane * 8;
  const short* Vb = Vp + (((size_t)(n * NH + h)) << 17) + lane * 8;

  // wave wk owns 32-key blocks kb32 = 4j + 2wk + {0,1}; 2x-unrolled ping-pong
  bf16x8 K0[2][2], V0[4], K1[2][2], V1[4];
  LOADK(K0, 2 * wk);
  LOADV(V0, 2 * wk);
  for (int it = 0; it < 32; it += 2) {
    const int kA = 2 * it + 2 * wk;  // even sub-round's kb32
    LOADK(K1, kA + 1);
    LOADV(V1, kA + 1);
    ATTN_STEP(K0, V0);
    if (it + 2 < 32) {
      LOADK(K0, kA + 4);
      LOADV(V0, kA + 4);
    }
    ATTN_STEP(K1, V1);
  }

  // ---- finish l: reduce across G groups (sum over this wave's keys)
#pragma unroll
  for (int nt = 0; nt < 4; ++nt) {
    lacc[nt] += __shfl_xor(lacc[nt], 16);
    lacc[nt] += __shfl_xor(lacc[nt], 32);
  }

  // ---- 2-way cross-wave reduction over wk (dedicated LDS, one barrier)
  if (wk == 1) {
#pragma unroll
    for (int nt = 0; nt < 4; ++nt) {
      const int q = 16 * nt + lb;
#pragma unroll
      for (int mtd = 0; mtd < 4; ++mtd)
        *(f32x4*)&red[wq][q][16 * mtd + 4 * G] = O[mtd][nt];
      if (G == 0) lred[wq * 64 + q] = lacc[nt];
    }
  }
  __syncthreads();
  if (wk == 0) {
    short* Ao = Ab + ((size_t)(n * SL + (qt << 7) + 64 * wq)) * EMB + h * HD;
#pragma unroll
    for (int nt = 0; nt < 4; ++nt) {
      const int q = 16 * nt + lb;
      const float inv = 1.f / (lacc[nt] + lred[wq * 64 + q]);
#pragma unroll
      for (int mtd = 0; mtd < 4; ++mtd) {
        const f32x4 t = *(const f32x4*)&red[wq][q][16 * mtd + 4 * G];
        const f32x4 s = t + O[mtd][nt];
        const short4 o = {f2b(s[0] * inv), f2b(s[1] * inv), f2b(s[2] * inv),
                          f2b(s[3] * inv)};
        *(short4*)(Ao + (size_t)q * EMB + 16 * mtd + 4 * G) = o;
      }
    }
  }
}

extern "C" void kernel_launch(void* const* d_in, const int* in_sizes, int n_in,
                              void* d_out, int out_size, void* d_ws, size_t ws_size,
                              hipStream_t stream) {
  const float* x  = (const float*)d_in[0];
  const float* Wq = (const float*)d_in[1];
  const float* Wk = (const float*)d_in[2];
  const float* Wv = (const float*)d_in[3];
  const float* Wo = (const float*)d_in[4];
  const float* bo = (const float*)d_in[5];
  float* out = (float*)d_out;

  // ws (bf16 elements): xb 4M | wqkv 3M | wob 1M | qb 4M | kb 4M | vt 4M = 40 MB
  short* xb   = (short*)d_ws;
  short* wqkv = xb + PROJ;
  short* wob  = wqkv + 3u * EMB * EMB;
  short* qb   = wob + (size_t)EMB * EMB;
  short* kb   = qb + PROJ;
  short* vt   = kb + PROJ;
  short* ab   = qb;  // alias: block-disjoint read-then-write regions

  cast_all<<<8192, 256, 0, stream>>>(x, Wq, Wk, Wv, Wo, xb, wqkv, wob);
  gemm_qkv<<<dim3(24, 32), 256, 0, stream>>>(xb, wqkv, qb, kb, vt);
  attn_mfma<<<dim3(NH, SL / 128, NB), 256, 0, stream>>>(qb, kb, vt, ab);
  gemm_out<<<dim3(16, 32), 256, 0, stream>>>(ab, wob, bo, out);
}

// Round 3
// 174.880 us; speedup vs baseline: 1.0195x; 1.0036x over previous
//
#include <hip/hip_runtime.h>
#include <hip/hip_bf16.h>

constexpr int NB  = 2;
constexpr int SL  = 2048;
constexpr int EMB = 1024;
constexpr int NH  = 16;
constexpr int HD  = 64;
constexpr int MT  = NB * SL;               // 4096 rows for projection GEMMs
constexpr size_t PROJ = (size_t)MT * EMB;  // 4M elements per [N,L,E] buffer

typedef __attribute__((ext_vector_type(8))) short bf16x8;  // 8 bf16 (4 VGPRs)
typedef __attribute__((ext_vector_type(4))) float f32x4;   // MFMA C/D frag

__device__ inline short f2b(float f) {
  __hip_bfloat16 b = __float2bfloat16(f);
  short s; __builtin_memcpy(&s, &b, 2); return s;
}

#define GLDS16(g, l)                                                     \
  __builtin_amdgcn_global_load_lds(                                      \
      (const __attribute__((address_space(1))) void*)(g),                \
      (__attribute__((address_space(3))) void*)(l), 16, 0, 0)

// ---------------------------------------------------------------------------
// Cast fp32 -> bf16: x -> xb, {Wq,Wk,Wv} -> wqkv (concat rows), Wo -> wob.
// ---------------------------------------------------------------------------
__global__ __launch_bounds__(256) void cast_all(
    const float* __restrict__ x,  const float* __restrict__ wq,
    const float* __restrict__ wk, const float* __restrict__ wv,
    const float* __restrict__ wo, short* __restrict__ xb,
    short* __restrict__ wqkv, short* __restrict__ wob) {
  const size_t t = (size_t)blockIdx.x * 256 + threadIdx.x;  // float4 index
  const float* src; short* dst; size_t base;
  if (t < 1048576)      { src = x;  dst = xb;              base = 0; }
  else if (t < 1310720) { src = wq; dst = wqkv;            base = 1048576; }
  else if (t < 1572864) { src = wk; dst = wqkv + (1 << 20); base = 1310720; }
  else if (t < 1835008) { src = wv; dst = wqkv + (2 << 20); base = 1572864; }
  else                  { src = wo; dst = wob;             base = 1835008; }
  const size_t i = t - base;
  const float4 v = ((const float4*)src)[i];
  const short4 o = {f2b(v.x), f2b(v.y), f2b(v.z), f2b(v.w)};
  ((short4*)dst)[i] = o;
}

// ---------------------------------------------------------------------------
// QKV GEMM: C = x[4096][1024] @ wqkv[3072][1024]^T.
// 128x128 tile, BK=64 (32 MFMA per barrier pair, half the vmcnt(0)+barrier
// drains of BK=32). LDS row stride = 128 B -> 16-way bank alias, fixed with
// the involutive 16B-chunk XOR swizzle (chunk ^= row&7), applied per rule
// #21: linear global_load_lds dest + inverse-swizzled per-lane GLOBAL source
// + swizzled read index. K order unchanged -> bit-identical numerics.
// Epilogue per n-region (unchanged from verified v8):
//   0 -> Q * (log2e/32), row-major;  1 -> K fragment-blocked;
//   2 -> V fragment-blocked (PV key-permutation folded).
// ---------------------------------------------------------------------------
__global__ __launch_bounds__(256) void gemm_qkv(
    const short* __restrict__ A, const short* __restrict__ W,
    short* __restrict__ qb, short* __restrict__ kb, short* __restrict__ vt) {
  __shared__ short As[128 * 64];
  __shared__ short Bs[128 * 64];
  const int tid = threadIdx.x;
  const int w = tid >> 6, lane = tid & 63;
  const int la = lane >> 4, lb = lane & 15;
  const int wm = w & 1, wn = w >> 1;
  const int m0 = blockIdx.y << 7, n0 = blockIdx.x << 7;
  // staging: wave w owns rows [32w,32w+32), 4 GLDS of 8 rows each.
  // lane -> row 8g+(lane>>3), chunk lane&7. row&7 == lane>>3, so the
  // inverse-swizzled global col chunk = (lane&7) ^ (lane>>3).
  const int srow = lane >> 3;
  const int scol = ((lane & 7) ^ srow) << 3;  // shorts
  const short* a0 = A + (size_t)(m0 + w * 32 + srow) * 1024 + scol;
  const short* b0 = W + (size_t)(n0 + w * 32 + srow) * 1024 + scol;
  short* lAw = As + (w * 32) * 64;
  short* lBw = Bs + (w * 32) * 64;

  f32x4 acc[4][4];
#pragma unroll
  for (int i = 0; i < 4; ++i)
#pragma unroll
    for (int j = 0; j < 4; ++j) acc[i][j] = (f32x4){0.f, 0.f, 0.f, 0.f};

  for (int k0 = 0; k0 < 1024; k0 += 64) {
    __syncthreads();
#pragma unroll
    for (int g = 0; g < 4; ++g) GLDS16(a0 + g * 8 * 1024 + k0, lAw + g * 8 * 64);
#pragma unroll
    for (int g = 0; g < 4; ++g) GLDS16(b0 + g * 8 * 1024 + k0, lBw + g * 8 * 64);
    __syncthreads();
#pragma unroll
    for (int ks = 0; ks < 2; ++ks) {
      bf16x8 af[4], bfr[4];
#pragma unroll
      for (int i = 0; i < 4; ++i) {
        const int row = wm * 64 + i * 16 + lb;
        af[i] = *(const bf16x8*)&As[row * 64 + (((ks << 2) + la) ^ (row & 7)) * 8];
      }
#pragma unroll
      for (int j = 0; j < 4; ++j) {
        const int row = wn * 64 + j * 16 + lb;
        bfr[j] = *(const bf16x8*)&Bs[row * 64 + (((ks << 2) + la) ^ (row & 7)) * 8];
      }
#pragma unroll
      for (int i = 0; i < 4; ++i)
#pragma unroll
        for (int j = 0; j < 4; ++j)
          acc[i][j] = __builtin_amdgcn_mfma_f32_16x16x32_bf16(af[i], bfr[j],
                                                              acc[i][j], 0, 0, 0);
    }
  }

  const int region = n0 >> 10;  // block-uniform (n-tile 128 < 1024)
  if (region == 0) {
    const float sc = 0.03125f * 1.44269504f;  // 1/sqrt(1024) * log2(e)
#pragma unroll
    for (int j = 0; j < 4; ++j) {
      const int nj = (n0 & 1023) + wn * 64 + j * 16 + lb;
#pragma unroll
      for (int i = 0; i < 4; ++i) {
        const int mi = m0 + wm * 64 + i * 16 + la * 4;
#pragma unroll
        for (int r = 0; r < 4; ++r)
          qb[(size_t)(mi + r) * 1024 + nj] = f2b(acc[i][j][r] * sc);
      }
    }
  } else if (region == 1) {
    // K fragment-blocked
#pragma unroll
    for (int j = 0; j < 4; ++j) {
      const int nj = (n0 & 1023) + wn * 64 + j * 16 + lb;
      const int hh = nj >> 6, d = nj & 63;
      const int ks = d >> 5, Gd = (d >> 3) & 3, jj = d & 7;
#pragma unroll
      for (int i = 0; i < 4; ++i) {
        const int mi = m0 + wm * 64 + i * 16 + la * 4;
        const int nbi = mi >> 11, seq = mi & (SL - 1);
        const size_t base = ((size_t)(nbi * NH + hh) << 17) +
                            (size_t)(seq >> 4) * 1024 + ks * 512 + Gd * 128 +
                            (seq & 15) * 8 + jj;
#pragma unroll
        for (int r = 0; r < 4; ++r) kb[base + r * 8] = f2b(acc[i][j][r]);
      }
    }
  } else {
    // V fragment-blocked (PV key-permutation folded in)
#pragma unroll
    for (int j = 0; j < 4; ++j) {
      const int nv = (n0 - 2048) + wn * 64 + j * 16 + lb;
      const int hh = nv >> 6, d = nv & 63;
      const int mtd = d >> 4, lbv = d & 15;
#pragma unroll
      for (int i = 0; i < 4; ++i) {
        const int mi = m0 + wm * 64 + i * 16 + la * 4;
        const int nbi = mi >> 11, seq = mi & (SL - 1);
        const int kq = seq >> 5, g = (seq >> 2) & 3, hi = (seq >> 4) & 1;
        const short4 o = {f2b(acc[i][j][0]), f2b(acc[i][j][1]),
                          f2b(acc[i][j][2]), f2b(acc[i][j][3])};
        *(short4*)&vt[((size_t)(nbi * NH + hh) << 17) + (size_t)kq * 2048 +
                      mtd * 512 + g * 128 + lbv * 8 + 4 * hi] = o;
      }
    }
  }
}

// ---------------------------------------------------------------------------
// Out GEMM: out = ab[4096][1024](bf16) @ wob[1024][1024]^T + bias, fp32 out.
// 128m x 64n tile, BK=64: 16 MFMA per barrier pair (was 8) -> halves the
// per-MFMA share of the vmcnt(0)+barrier drain. Same XOR chunk swizzle.
// ---------------------------------------------------------------------------
__global__ __launch_bounds__(256) void gemm_out(
    const short* __restrict__ A, const short* __restrict__ W,
    const float* __restrict__ bias, float* __restrict__ out) {
  __shared__ short As[128 * 64];
  __shared__ short Bs[64 * 64];
  const int tid = threadIdx.x;
  const int w = tid >> 6, lane = tid & 63;
  const int la = lane >> 4, lb = lane & 15;
  const int wm = w & 1, wn = w >> 1;
  const int m0 = blockIdx.y << 7, n0 = blockIdx.x << 6;
  const int srow = lane >> 3;
  const int scol = ((lane & 7) ^ srow) << 3;
  const short* a0 = A + (size_t)(m0 + w * 32 + srow) * 1024 + scol;
  const short* b0 = W + (size_t)(n0 + w * 16 + srow) * 1024 + scol;
  short* lAw = As + (w * 32) * 64;
  short* lBw = Bs + (w * 16) * 64;

  f32x4 acc[4][2];
#pragma unroll
  for (int i = 0; i < 4; ++i)
#pragma unroll
    for (int j = 0; j < 2; ++j) acc[i][j] = (f32x4){0.f, 0.f, 0.f, 0.f};

  for (int k0 = 0; k0 < 1024; k0 += 64) {
    __syncthreads();
#pragma unroll
    for (int g = 0; g < 4; ++g) GLDS16(a0 + g * 8 * 1024 + k0, lAw + g * 8 * 64);
#pragma unroll
    for (int g = 0; g < 2; ++g) GLDS16(b0 + g * 8 * 1024 + k0, lBw + g * 8 * 64);
    __syncthreads();
#pragma unroll
    for (int ks = 0; ks < 2; ++ks) {
      bf16x8 af[4], bfr[2];
#pragma unroll
      for (int i = 0; i < 4; ++i) {
        const int row = wm * 64 + i * 16 + lb;
        af[i] = *(const bf16x8*)&As[row * 64 + (((ks << 2) + la) ^ (row & 7)) * 8];
      }
#pragma unroll
      for (int j = 0; j < 2; ++j) {
        const int row = wn * 32 + j * 16 + lb;
        bfr[j] = *(const bf16x8*)&Bs[row * 64 + (((ks << 2) + la) ^ (row & 7)) * 8];
      }
#pragma unroll
      for (int i = 0; i < 4; ++i)
#pragma unroll
        for (int j = 0; j < 2; ++j)
          acc[i][j] = __builtin_amdgcn_mfma_f32_16x16x32_bf16(af[i], bfr[j],
                                                              acc[i][j], 0, 0, 0);
    }
  }
#pragma unroll
  for (int j = 0; j < 2; ++j) {
    const int nj = n0 + wn * 32 + j * 16 + lb;
    const float bv = bias[nj];
#pragma unroll
    for (int i = 0; i < 4; ++i) {
      const int mi = m0 + wm * 64 + i * 16 + la * 4;
#pragma unroll
      for (int r = 0; r < 4; ++r)
        out[(size_t)(mi + r) * 1024 + nj] = acc[i][j][r] + bv;
    }
  }
}

// ---------------------------------------------------------------------------
// Flash attention v9 = v8 (zero-LDS main loop, direct global->register K/V,
// 2x-unrolled static ping-pong) + T5 s_setprio around the MFMA clusters:
// waves free-run with no barriers (max phase diversity), the regime where
// setprio measured +4-7% on attention (m191).
// ---------------------------------------------------------------------------
#define LOADK(DK, KB32)                                                      \
  do {                                                                       \
    _Pragma("unroll") for (int rr_ = 0; rr_ < 2; ++rr_)                      \
        _Pragma("unroll") for (int ks_ = 0; ks_ < 2; ++ks_)                  \
            DK[rr_][ks_] = *(const bf16x8*)(Kb + (size_t)(KB32) * 2048 +     \
                                            rr_ * 1024 + ks_ * 512);         \
  } while (0)

#define LOADV(DV, KB32)                                                      \
  do {                                                                       \
    _Pragma("unroll") for (int md_ = 0; md_ < 4; ++md_)                      \
        DV[md_] = *(const bf16x8*)(Vb + (size_t)(KB32) * 2048 + md_ * 512);  \
  } while (0)

#define ATTN_STEP(AK, AV)                                                    \
  do {                                                                       \
    f32x4 S[2][4];                                                           \
    _Pragma("unroll") for (int mt = 0; mt < 2; ++mt)                         \
        _Pragma("unroll") for (int nt = 0; nt < 4; ++nt)                     \
            S[mt][nt] = (f32x4){0.f, 0.f, 0.f, 0.f};                         \
    __builtin_amdgcn_s_setprio(1);                                           \
    _Pragma("unroll") for (int ks = 0; ks < 2; ++ks)                         \
        _Pragma("unroll") for (int nt = 0; nt < 4; ++nt) {                   \
      S[0][nt] = __builtin_amdgcn_mfma_f32_16x16x32_bf16(AK[0][ks],          \
                     bQ[nt][ks], S[0][nt], 0, 0, 0);                         \
      S[1][nt] = __builtin_amdgcn_mfma_f32_16x16x32_bf16(AK[1][ks],          \
                     bQ[nt][ks], S[1][nt], 0, 0, 0);                         \
    }                                                                        \
    __builtin_amdgcn_s_setprio(0);                                           \
    _Pragma("unroll") for (int nt = 0; nt < 4; ++nt) {                       \
      _Pragma("unroll") for (int mt = 0; mt < 2; ++mt)                       \
          _Pragma("unroll") for (int r = 0; r < 4; ++r) {                    \
        const float p = __builtin_amdgcn_exp2f(S[mt][nt][r]);                \
        S[mt][nt][r] = p;                                                    \
        lacc[nt] += p;                                                       \
      }                                                                      \
      bf16x8 B2;                                                             \
      B2[0] = f2b(S[0][nt][0]); B2[1] = f2b(S[0][nt][1]);                    \
      B2[2] = f2b(S[0][nt][2]); B2[3] = f2b(S[0][nt][3]);                    \
      B2[4] = f2b(S[1][nt][0]); B2[5] = f2b(S[1][nt][1]);                    \
      B2[6] = f2b(S[1][nt][2]); B2[7] = f2b(S[1][nt][3]);                    \
      __builtin_amdgcn_s_setprio(1);                                         \
      _Pragma("unroll") for (int mtd = 0; mtd < 4; ++mtd)                    \
          O[mtd][nt] = __builtin_amdgcn_mfma_f32_16x16x32_bf16(              \
              AV[mtd], B2, O[mtd][nt], 0, 0, 0);                             \
      __builtin_amdgcn_s_setprio(0);                                         \
    }                                                                        \
  } while (0)

__global__ __launch_bounds__(256, 2) void attn_mfma(const short* __restrict__ Qg,
                                                    const short* __restrict__ Kp,
                                                    const short* __restrict__ Vp,
                                                    short* __restrict__ Ab) {
  __shared__ __align__(16) float red[2][64][68];  // 34816 B
  __shared__ float lred[128];
  const int tid = threadIdx.x;
  const int w = tid >> 6, lane = tid & 63;
  const int G = lane >> 4, lb = lane & 15;
  const int wk = w & 1, wq = w >> 1;
  const int h = blockIdx.x, qt = blockIdx.y, n = blockIdx.z;

  // ---- Q fragments: global -> regs, once. q = 64wq+16nt+lb, d = 32ks+8G
  const short* Qb = Qg + ((size_t)(n * SL + (qt << 7) + 64 * wq)) * EMB + h * HD;
  bf16x8 bQ[4][2];
#pragma unroll
  for (int nt = 0; nt < 4; ++nt)
#pragma unroll
    for (int ks = 0; ks < 2; ++ks)
      bQ[nt][ks] =
          *(const bf16x8*)(Qb + (size_t)(16 * nt + lb) * EMB + 32 * ks + 8 * G);

  f32x4 O[4][4];  // [mtd: d=16mtd+4G+r][nt: q=64wq+16nt+lb]
  float lacc[4] = {0.f, 0.f, 0.f, 0.f};
#pragma unroll
  for (int i = 0; i < 4; ++i)
#pragma unroll
    for (int j = 0; j < 4; ++j) O[i][j] = (f32x4){0.f, 0.f, 0.f, 0.f};

  // fragment-blocked bases; fold per-lane 16B chunk offset into the pointer
  const short* Kb = Kp + (((size_t)(n * NH + h)) << 17) + lane * 8;
  const short* Vb = Vp + (((size_t)(n * NH + h)) << 17) + lane * 8;

  // wave wk owns 32-key blocks kb32 = 4j + 2wk + {0,1}; 2x-unrolled ping-pong
  bf16x8 K0[2][2], V0[4], K1[2][2], V1[4];
  LOADK(K0, 2 * wk);
  LOADV(V0, 2 * wk);
  for (int it = 0; it < 32; it += 2) {
    const int kA = 2 * it + 2 * wk;  // even sub-round's kb32
    LOADK(K1, kA + 1);
    LOADV(V1, kA + 1);
    ATTN_STEP(K0, V0);
    if (it + 2 < 32) {
      LOADK(K0, kA + 4);
      LOADV(V0, kA + 4);
    }
    ATTN_STEP(K1, V1);
  }

  // ---- finish l: reduce across G groups (sum over this wave's keys)
#pragma unroll
  for (int nt = 0; nt < 4; ++nt) {
    lacc[nt] += __shfl_xor(lacc[nt], 16);
    lacc[nt] += __shfl_xor(lacc[nt], 32);
  }

  // ---- 2-way cross-wave reduction over wk (dedicated LDS, one barrier)
  if (wk == 1) {
#pragma unroll
    for (int nt = 0; nt < 4; ++nt) {
      const int q = 16 * nt + lb;
#pragma unroll
      for (int mtd = 0; mtd < 4; ++mtd)
        *(f32x4*)&red[wq][q][16 * mtd + 4 * G] = O[mtd][nt];
      if (G == 0) lred[wq * 64 + q] = lacc[nt];
    }
  }
  __syncthreads();
  if (wk == 0) {
    short* Ao = Ab + ((size_t)(n * SL + (qt << 7) + 64 * wq)) * EMB + h * HD;
#pragma unroll
    for (int nt = 0; nt < 4; ++nt) {
      const int q = 16 * nt + lb;
      const float inv = 1.f / (lacc[nt] + lred[wq * 64 + q]);
#pragma unroll
      for (int mtd = 0; mtd < 4; ++mtd) {
        const f32x4 t = *(const f32x4*)&red[wq][q][16 * mtd + 4 * G];
        const f32x4 s = t + O[mtd][nt];
        const short4 o = {f2b(s[0] * inv), f2b(s[1] * inv), f2b(s[2] * inv),
                          f2b(s[3] * inv)};
        *(short4*)(Ao + (size_t)q * EMB + 16 * mtd + 4 * G) = o;
      }
    }
  }
}

extern "C" void kernel_launch(void* const* d_in, const int* in_sizes, int n_in,
                              void* d_out, int out_size, void* d_ws, size_t ws_size,
                              hipStream_t stream) {
  const float* x  = (const float*)d_in[0];
  const float* Wq = (const float*)d_in[1];
  const float* Wk = (const float*)d_in[2];
  const float* Wv = (const float*)d_in[3];
  const float* Wo = (const float*)d_in[4];
  const float* bo = (const float*)d_in[5];
  float* out = (float*)d_out;

  // ws (bf16 elements): xb 4M | wqkv 3M | wob 1M | qb 4M | kb 4M | vt 4M = 40 MB
  short* xb   = (short*)d_ws;
  short* wqkv = xb + PROJ;
  short* wob  = wqkv + 3u * EMB * EMB;
  short* qb   = wob + (size_t)EMB * EMB;
  short* kb   = qb + PROJ;
  short* vt   = kb + PROJ;
  short* ab   = qb;  // alias: block-disjoint read-then-write regions

  cast_all<<<8192, 256, 0, stream>>>(x, Wq, Wk, Wv, Wo, xb, wqkv, wob);
  gemm_qkv<<<dim3(24, 32), 256, 0, stream>>>(xb, wqkv, qb, kb, vt);
  attn_mfma<<<dim3(NH, SL / 128, NB), 256, 0, stream>>>(qb, kb, vt, ab);
  gemm_out<<<dim3(16, 32), 256, 0, stream>>>(ab, wob, bo, out);
}

// Round 4
// 173.266 us; speedup vs baseline: 1.0290x; 1.0093x over previous
//
#include <hip/hip_runtime.h>
#include <hip/hip_bf16.h>

constexpr int NB  = 2;
constexpr int SL  = 2048;
constexpr int EMB = 1024;
constexpr int NH  = 16;
constexpr int HD  = 64;
constexpr int MT  = NB * SL;               // 4096 rows for projection GEMMs
constexpr size_t PROJ = (size_t)MT * EMB;  // 4M elements per [N,L,E] buffer

typedef __attribute__((ext_vector_type(8))) short bf16x8;  // 8 bf16 (4 VGPRs)
typedef __attribute__((ext_vector_type(4))) float f32x4;   // MFMA C/D frag

__device__ inline short f2b(float f) {
  __hip_bfloat16 b = __float2bfloat16(f);
  short s; __builtin_memcpy(&s, &b, 2); return s;
}

#define GLDS16(g, l)                                                     \
  __builtin_amdgcn_global_load_lds(                                      \
      (const __attribute__((address_space(1))) void*)(g),                \
      (__attribute__((address_space(3))) void*)(l), 16, 0, 0)

// ---------------------------------------------------------------------------
// Cast fp32 -> bf16: x -> xb, {Wq,Wk,Wv} -> wqkv (concat rows), Wo -> wob.
// ---------------------------------------------------------------------------
__global__ __launch_bounds__(256) void cast_all(
    const float* __restrict__ x,  const float* __restrict__ wq,
    const float* __restrict__ wk, const float* __restrict__ wv,
    const float* __restrict__ wo, short* __restrict__ xb,
    short* __restrict__ wqkv, short* __restrict__ wob) {
  const size_t t = (size_t)blockIdx.x * 256 + threadIdx.x;  // float4 index
  const float* src; short* dst; size_t base;
  if (t < 1048576)      { src = x;  dst = xb;              base = 0; }
  else if (t < 1310720) { src = wq; dst = wqkv;            base = 1048576; }
  else if (t < 1572864) { src = wk; dst = wqkv + (1 << 20); base = 1310720; }
  else if (t < 1835008) { src = wv; dst = wqkv + (2 << 20); base = 1572864; }
  else                  { src = wo; dst = wob;             base = 1835008; }
  const size_t i = t - base;
  const float4 v = ((const float4*)src)[i];
  const short4 o = {f2b(v.x), f2b(v.y), f2b(v.z), f2b(v.w)};
  ((short4*)dst)[i] = o;
}

// ---------------------------------------------------------------------------
// QKV GEMM, 8-phase 256x256 schedule (T2+T3+T4+T5):
//   C = x[4096][1024] @ wqkv[3072][1024]^T,  grid 192 blocks, 512 thr (8 waves
//   2Mx4N, 128x64 out/wave), BK=64, LDS 128 KiB = 2 dbuf x (A 256x64 + B
//   256x64) bf16. 8 phases per iteration (2 K-tiles). Per phase: ds_read reg
//   subtile | stage 1 half-tile (2x global_load_lds w16) | raw s_barrier |
//   setprio(1) 16 MFMA setprio(0) | barrier. vmcnt(2) gates ONLY at phases
//   4+8 (counted, never 0 in main loop); peeled tail drains to 0.
//   Slot lifecycle ledger (verified): each half-tile slot's last read phase
//   precedes its restage phase across a barrier; each gate+barrier forces
//   completion of exactly the half-tiles read in the following 4 phases.
//   LDS chunk-XOR swizzle (chunk ^= row&7): linear GLDS dest + pre-swizzled
//   per-lane global source + swizzled ds_read (HW-verified in prior round).
//   K order unchanged -> bit-identical numerics. Epilogues as before:
//   0 -> Q*(log2e/32) row-major; 1 -> K fragment-blocked; 2 -> V frag-blocked.
// ---------------------------------------------------------------------------
#define QBAR() asm volatile("s_barrier" ::: "memory")
#define QVM(n) asm volatile("s_waitcnt vmcnt(" #n ")" ::: "memory")

#define STAGEH(gh, lh)                                                   \
  do {                                                                   \
    GLDS16((gh) + go0, (lh) + w16 * 64);                                 \
    GLDS16((gh) + go1, (lh) + w16 * 64 + 512);                           \
  } while (0)

#define LDAQ(pa, ks)                                                     \
  _Pragma("unroll") for (int i_ = 0; i_ < 8; ++i_)                       \
      aR[i_] = *(const bf16x8*)&(pa)[(wm128 + i_ * 16 + lb) * 64 +       \
                                     ((((ks) << 2) + G) ^ lb7) * 8];

#define LDBQ(dst, pb, j0, ks)                                            \
  dst[0] = *(const bf16x8*)&(pb)[(wn64 + (j0) * 16 + lb) * 64 +          \
                                 ((((ks) << 2) + G) ^ lb7) * 8];         \
  dst[1] = *(const bf16x8*)&(pb)[(wn64 + ((j0) + 1) * 16 + lb) * 64 +    \
                                 ((((ks) << 2) + G) ^ lb7) * 8];

#define MMQ(bp, j0)                                                      \
  __builtin_amdgcn_s_setprio(1);                                         \
  _Pragma("unroll") for (int i_ = 0; i_ < 8; ++i_) {                     \
    acc[i_][j0] = __builtin_amdgcn_mfma_f32_16x16x32_bf16(               \
        aR[i_], bp[0], acc[i_][j0], 0, 0, 0);                            \
    acc[i_][(j0) + 1] = __builtin_amdgcn_mfma_f32_16x16x32_bf16(         \
        aR[i_], bp[1], acc[i_][(j0) + 1], 0, 0, 0);                      \
  }                                                                      \
  __builtin_amdgcn_s_setprio(0);

__global__ __launch_bounds__(512, 2) void gemm_qkv(
    const short* __restrict__ A, const short* __restrict__ W,
    short* __restrict__ qb, short* __restrict__ kb, short* __restrict__ vt) {
  extern __shared__ short lds[];
  const int tid = threadIdx.x;
  const int w = tid >> 6, lane = tid & 63;
  const int G = lane >> 4, lb = lane & 15, lb7 = lb & 7;
  const int wm = w >> 2, wn = w & 3;
  const int wm128 = wm * 128, wn64 = wn * 64;
  // XCD-bijective swizzle: 192 = 8 XCD x 24; chunk = 2 m-rows x 12 n-cols.
  const int bid = blockIdx.x;
  const int swz = (bid & 7) * 24 + (bid >> 3);
  const int by = swz / 12, bx = swz % 12;
  const int m0 = by << 8, n0 = bx << 8;
  // staging geometry: wave w stages rows [w*16,+16) of each half-tile.
  // lane -> row w16+g*8+(lane>>3), LDS chunk lane&7; row&7 == lane>>3, so the
  // inverse-swizzled global chunk = (lane&7)^(lane>>3).
  const int w16 = w * 16;
  const int lr = lane >> 3;
  const int lc = ((lane & 7) ^ lr) << 3;  // shorts
  const size_t go0 = (size_t)(w16 + lr) * 1024 + lc;
  const size_t go1 = go0 + (size_t)8 * 1024;
  // global half bases (A halves = m rows, B halves = n rows); tile t -> +t*64
  const short* aH0 = A + (size_t)m0 * 1024;
  const short* aH1 = A + (size_t)(m0 + 128) * 1024;
  const short* bH0 = W + (size_t)n0 * 1024;
  const short* bH1 = W + (size_t)(n0 + 128) * 1024;
  // LDS layout (shorts): buf0{A,B} buf1{A,B}, each tile 256x64, half = 8192
  short* a0s = lds;
  short* b0s = lds + 16384;
  short* a1s = lds + 32768;
  short* b1s = lds + 49152;

  f32x4 acc[8][4];
#pragma unroll
  for (int i = 0; i < 8; ++i)
#pragma unroll
    for (int j = 0; j < 4; ++j) acc[i][j] = (f32x4){0.f, 0.f, 0.f, 0.f};
  bf16x8 aR[8], b01[2], b23[2];

  // prologue: tiles 0 -> buf0, 1 -> buf1 (16 GLDS); wait tile0 (8 left)
  STAGEH(aH0, a0s);
  STAGEH(aH1, a0s + 8192);
  STAGEH(bH0, b0s);
  STAGEH(bH1, b0s + 8192);
  STAGEH(aH0 + 64, a1s);
  STAGEH(aH1 + 64, a1s + 8192);
  STAGEH(bH0 + 64, b1s);
  STAGEH(bH1 + 64, b1s + 8192);
  QVM(8);
  QBAR();

  for (int it = 0; it < 7; ++it) {
    const size_t k1 = (size_t)(2 * it + 1) * 64;  // tb of this iter
    const size_t k2 = (size_t)(2 * it + 2) * 64;  // next even tile -> buf0
    const size_t k3 = (size_t)(2 * it + 3) * 64;  // next odd tile  -> buf1
    // ---- tile 2it from buf0
    // P1
    LDAQ(a0s, 0);
    LDBQ(b01, b0s, 0, 0);
    if (it > 0) STAGEH(aH1 + k1, a1s + 8192);
    QBAR(); MMQ(b01, 0); QBAR();
    // P2
    LDBQ(b23, b0s, 2, 0);
    if (it > 0) STAGEH(bH0 + k1, b1s);
    QBAR(); MMQ(b23, 2); QBAR();
    // P3
    LDAQ(a0s, 1);
    LDBQ(b01, b0s, 0, 1);
    if (it > 0) STAGEH(bH1 + k1, b1s + 8192);
    QBAR(); MMQ(b01, 0); QBAR();
    // P4  (gate: forces all stages except this phase's -> buf1 tile complete)
    LDBQ(b23, b0s, 2, 1);
    STAGEH(aH0 + k2, a0s);
    QVM(2);
    QBAR(); MMQ(b23, 2); QBAR();
    // ---- tile 2it+1 from buf1
    // P5
    LDAQ(a1s, 0);
    LDBQ(b01, b1s, 0, 0);
    STAGEH(aH1 + k2, a0s + 8192);
    QBAR(); MMQ(b01, 0); QBAR();
    // P6
    LDBQ(b23, b1s, 2, 0);
    STAGEH(bH0 + k2, b0s);
    QBAR(); MMQ(b23, 2); QBAR();
    // P7
    LDAQ(a1s, 1);
    LDBQ(b01, b1s, 0, 1);
    STAGEH(bH1 + k2, b0s + 8192);
    QBAR(); MMQ(b01, 0); QBAR();
    // P8  (gate: forces P4-P7 stages -> buf0 tile complete for next iter)
    LDBQ(b23, b1s, 2, 1);
    STAGEH(aH0 + k3, a1s);
    QVM(2);
    QBAR(); MMQ(b23, 2); QBAR();
  }
  // ---- peeled tail: tiles 14 (buf0) / 15 (buf1); finish tile15 stage, drain
  {
    const size_t k1 = (size_t)15 * 64;
    LDAQ(a0s, 0); LDBQ(b01, b0s, 0, 0);
    STAGEH(aH1 + k1, a1s + 8192);
    QBAR(); MMQ(b01, 0); QBAR();
    LDBQ(b23, b0s, 2, 0);
    STAGEH(bH0 + k1, b1s);
    QBAR(); MMQ(b23, 2); QBAR();
    LDAQ(a0s, 1); LDBQ(b01, b0s, 0, 1);
    STAGEH(bH1 + k1, b1s + 8192);
    QBAR(); MMQ(b01, 0); QBAR();
    LDBQ(b23, b0s, 2, 1);
    QVM(0);
    QBAR(); MMQ(b23, 2); QBAR();
    LDAQ(a1s, 0); LDBQ(b01, b1s, 0, 0);
    QBAR(); MMQ(b01, 0); QBAR();
    LDBQ(b23, b1s, 2, 0);
    QBAR(); MMQ(b23, 2); QBAR();
    LDAQ(a1s, 1); LDBQ(b01, b1s, 0, 1);
    QBAR(); MMQ(b01, 0); QBAR();
    LDBQ(b23, b1s, 2, 1);
    QBAR(); MMQ(b23, 2); QBAR();
  }

  // ---- epilogue (same region layouts as before; wave tile = 128m x 64n)
  const int region = n0 >> 10;  // 256-wide tiles never cross 1024 boundaries
  if (region == 0) {
    const float sc = 0.03125f * 1.44269504f;  // 1/sqrt(1024) * log2(e)
#pragma unroll
    for (int j = 0; j < 4; ++j) {
      const int nj = (n0 & 1023) + wn64 + j * 16 + lb;
#pragma unroll
      for (int i = 0; i < 8; ++i) {
        const int mi = m0 + wm128 + i * 16 + (G << 2);
#pragma unroll
        for (int r = 0; r < 4; ++r)
          qb[(size_t)(mi + r) * 1024 + nj] = f2b(acc[i][j][r] * sc);
      }
    }
  } else if (region == 1) {
    // K fragment-blocked
#pragma unroll
    for (int j = 0; j < 4; ++j) {
      const int nj = (n0 & 1023) + wn64 + j * 16 + lb;
      const int hh = nj >> 6, d = nj & 63;
      const int ks = d >> 5, Gd = (d >> 3) & 3, jj = d & 7;
#pragma unroll
      for (int i = 0; i < 8; ++i) {
        const int mi = m0 + wm128 + i * 16 + (G << 2);
        const int nbi = mi >> 11, seq = mi & (SL - 1);
        const size_t base = ((size_t)(nbi * NH + hh) << 17) +
                            (size_t)(seq >> 4) * 1024 + ks * 512 + Gd * 128 +
                            (seq & 15) * 8 + jj;
#pragma unroll
        for (int r = 0; r < 4; ++r) kb[base + r * 8] = f2b(acc[i][j][r]);
      }
    }
  } else {
    // V fragment-blocked (PV key-permutation folded in)
#pragma unroll
    for (int j = 0; j < 4; ++j) {
      const int nv = (n0 - 2048) + wn64 + j * 16 + lb;
      const int hh = nv >> 6, d = nv & 63;
      const int mtd = d >> 4, lbv = d & 15;
#pragma unroll
      for (int i = 0; i < 8; ++i) {
        const int mi = m0 + wm128 + i * 16 + (G << 2);
        const int nbi = mi >> 11, seq = mi & (SL - 1);
        const int kq = seq >> 5, g = (seq >> 2) & 3, hi = (seq >> 4) & 1;
        const short4 o = {f2b(acc[i][j][0]), f2b(acc[i][j][1]),
                          f2b(acc[i][j][2]), f2b(acc[i][j][3])};
        *(short4*)&vt[((size_t)(nbi * NH + hh) << 17) + (size_t)kq * 2048 +
                      mtd * 512 + g * 128 + lbv * 8 + 4 * hi] = o;
      }
    }
  }
}

// ---------------------------------------------------------------------------
// Out GEMM: out = ab[4096][1024](bf16) @ wob[1024][1024]^T + bias, fp32 out.
// 128m x 64n tile, BK=64, chunk-XOR swizzle (round-3 passing version).
// ---------------------------------------------------------------------------
__global__ __launch_bounds__(256) void gemm_out(
    const short* __restrict__ A, const short* __restrict__ W,
    const float* __restrict__ bias, float* __restrict__ out) {
  __shared__ short As[128 * 64];
  __shared__ short Bs[64 * 64];
  const int tid = threadIdx.x;
  const int w = tid >> 6, lane = tid & 63;
  const int la = lane >> 4, lb = lane & 15;
  const int wm = w & 1, wn = w >> 1;
  const int m0 = blockIdx.y << 7, n0 = blockIdx.x << 6;
  const int srow = lane >> 3;
  const int scol = ((lane & 7) ^ srow) << 3;
  const short* a0 = A + (size_t)(m0 + w * 32 + srow) * 1024 + scol;
  const short* b0 = W + (size_t)(n0 + w * 16 + srow) * 1024 + scol;
  short* lAw = As + (w * 32) * 64;
  short* lBw = Bs + (w * 16) * 64;

  f32x4 acc[4][2];
#pragma unroll
  for (int i = 0; i < 4; ++i)
#pragma unroll
    for (int j = 0; j < 2; ++j) acc[i][j] = (f32x4){0.f, 0.f, 0.f, 0.f};

  for (int k0 = 0; k0 < 1024; k0 += 64) {
    __syncthreads();
#pragma unroll
    for (int g = 0; g < 4; ++g) GLDS16(a0 + g * 8 * 1024 + k0, lAw + g * 8 * 64);
#pragma unroll
    for (int g = 0; g < 2; ++g) GLDS16(b0 + g * 8 * 1024 + k0, lBw + g * 8 * 64);
    __syncthreads();
#pragma unroll
    for (int ks = 0; ks < 2; ++ks) {
      bf16x8 af[4], bfr[2];
#pragma unroll
      for (int i = 0; i < 4; ++i) {
        const int row = wm * 64 + i * 16 + lb;
        af[i] = *(const bf16x8*)&As[row * 64 + (((ks << 2) + la) ^ (row & 7)) * 8];
      }
#pragma unroll
      for (int j = 0; j < 2; ++j) {
        const int row = wn * 32 + j * 16 + lb;
        bfr[j] = *(const bf16x8*)&Bs[row * 64 + (((ks << 2) + la) ^ (row & 7)) * 8];
      }
#pragma unroll
      for (int i = 0; i < 4; ++i)
#pragma unroll
        for (int j = 0; j < 2; ++j)
          acc[i][j] = __builtin_amdgcn_mfma_f32_16x16x32_bf16(af[i], bfr[j],
                                                              acc[i][j], 0, 0, 0);
    }
  }
#pragma unroll
  for (int j = 0; j < 2; ++j) {
    const int nj = n0 + wn * 32 + j * 16 + lb;
    const float bv = bias[nj];
#pragma unroll
    for (int i = 0; i < 4; ++i) {
      const int mi = m0 + wm * 64 + i * 16 + la * 4;
#pragma unroll
      for (int r = 0; r < 4; ++r)
        out[(size_t)(mi + r) * 1024 + nj] = acc[i][j][r] + bv;
    }
  }
}

// ---------------------------------------------------------------------------
// Flash attention v9 (round-3 passing version): zero-LDS main loop, direct
// global->register K/V (fragment-blocked layouts), 2x-unrolled static
// ping-pong, setprio around MFMA clusters.
// ---------------------------------------------------------------------------
#define LOADK(DK, KB32)                                                      \
  do {                                                                       \
    _Pragma("unroll") for (int rr_ = 0; rr_ < 2; ++rr_)                      \
        _Pragma("unroll") for (int ks_ = 0; ks_ < 2; ++ks_)                  \
            DK[rr_][ks_] = *(const bf16x8*)(Kb + (size_t)(KB32) * 2048 +     \
                                            rr_ * 1024 + ks_ * 512);         \
  } while (0)

#define LOADV(DV, KB32)                                                      \
  do {                                                                       \
    _Pragma("unroll") for (int md_ = 0; md_ < 4; ++md_)                      \
        DV[md_] = *(const bf16x8*)(Vb + (size_t)(KB32) * 2048 + md_ * 512);  \
  } while (0)

#define ATTN_STEP(AK, AV)                                                    \
  do {                                                                       \
    f32x4 S[2][4];                                                           \
    _Pragma("unroll") for (int mt = 0; mt < 2; ++mt)                         \
        _Pragma("unroll") for (int nt = 0; nt < 4; ++nt)                     \
            S[mt][nt] = (f32x4){0.f, 0.f, 0.f, 0.f};                         \
    __builtin_amdgcn_s_setprio(1);                                           \
    _Pragma("unroll") for (int ks = 0; ks < 2; ++ks)                         \
        _Pragma("unroll") for (int nt = 0; nt < 4; ++nt) {                   \
      S[0][nt] = __builtin_amdgcn_mfma_f32_16x16x32_bf16(AK[0][ks],          \
                     bQ[nt][ks], S[0][nt], 0, 0, 0);                         \
      S[1][nt] = __builtin_amdgcn_mfma_f32_16x16x32_bf16(AK[1][ks],          \
                     bQ[nt][ks], S[1][nt], 0, 0, 0);                         \
    }                                                                        \
    __builtin_amdgcn_s_setprio(0);                                           \
    _Pragma("unroll") for (int nt = 0; nt < 4; ++nt) {                       \
      _Pragma("unroll") for (int mt = 0; mt < 2; ++mt)                       \
          _Pragma("unroll") for (int r = 0; r < 4; ++r) {                    \
        const float p = __builtin_amdgcn_exp2f(S[mt][nt][r]);                \
        S[mt][nt][r] = p;                                                    \
        lacc[nt] += p;                                                       \
      }                                                                      \
      bf16x8 B2;                                                             \
      B2[0] = f2b(S[0][nt][0]); B2[1] = f2b(S[0][nt][1]);                    \
      B2[2] = f2b(S[0][nt][2]); B2[3] = f2b(S[0][nt][3]);                    \
      B2[4] = f2b(S[1][nt][0]); B2[5] = f2b(S[1][nt][1]);                    \
      B2[6] = f2b(S[1][nt][2]); B2[7] = f2b(S[1][nt][3]);                    \
      __builtin_amdgcn_s_setprio(1);                                         \
      _Pragma("unroll") for (int mtd = 0; mtd < 4; ++mtd)                    \
          O[mtd][nt] = __builtin_amdgcn_mfma_f32_16x16x32_bf16(              \
              AV[mtd], B2, O[mtd][nt], 0, 0, 0);                             \
      __builtin_amdgcn_s_setprio(0);                                         \
    }                                                                        \
  } while (0)

__global__ __launch_bounds__(256, 2) void attn_mfma(const short* __restrict__ Qg,
                                                    const short* __restrict__ Kp,
                                                    const short* __restrict__ Vp,
                                                    short* __restrict__ Ab) {
  __shared__ __align__(16) float red[2][64][68];  // 34816 B
  __shared__ float lred[128];
  const int tid = threadIdx.x;
  const int w = tid >> 6, lane = tid & 63;
  const int G = lane >> 4, lb = lane & 15;
  const int wk = w & 1, wq = w >> 1;
  const int h = blockIdx.x, qt = blockIdx.y, n = blockIdx.z;

  // ---- Q fragments: global -> regs, once. q = 64wq+16nt+lb, d = 32ks+8G
  const short* Qb = Qg + ((size_t)(n * SL + (qt << 7) + 64 * wq)) * EMB + h * HD;
  bf16x8 bQ[4][2];
#pragma unroll
  for (int nt = 0; nt < 4; ++nt)
#pragma unroll
    for (int ks = 0; ks < 2; ++ks)
      bQ[nt][ks] =
          *(const bf16x8*)(Qb + (size_t)(16 * nt + lb) * EMB + 32 * ks + 8 * G);

  f32x4 O[4][4];  // [mtd: d=16mtd+4G+r][nt: q=64wq+16nt+lb]
  float lacc[4] = {0.f, 0.f, 0.f, 0.f};
#pragma unroll
  for (int i = 0; i < 4; ++i)
#pragma unroll
    for (int j = 0; j < 4; ++j) O[i][j] = (f32x4){0.f, 0.f, 0.f, 0.f};

  // fragment-blocked bases; fold per-lane 16B chunk offset into the pointer
  const short* Kb = Kp + (((size_t)(n * NH + h)) << 17) + lane * 8;
  const short* Vb = Vp + (((size_t)(n * NH + h)) << 17) + lane * 8;

  // wave wk owns 32-key blocks kb32 = 4j + 2wk + {0,1}; 2x-unrolled ping-pong
  bf16x8 K0[2][2], V0[4], K1[2][2], V1[4];
  LOADK(K0, 2 * wk);
  LOADV(V0, 2 * wk);
  for (int it = 0; it < 32; it += 2) {
    const int kA = 2 * it + 2 * wk;  // even sub-round's kb32
    LOADK(K1, kA + 1);
    LOADV(V1, kA + 1);
    ATTN_STEP(K0, V0);
    if (it + 2 < 32) {
      LOADK(K0, kA + 4);
      LOADV(V0, kA + 4);
    }
    ATTN_STEP(K1, V1);
  }

  // ---- finish l: reduce across G groups (sum over this wave's keys)
#pragma unroll
  for (int nt = 0; nt < 4; ++nt) {
    lacc[nt] += __shfl_xor(lacc[nt], 16);
    lacc[nt] += __shfl_xor(lacc[nt], 32);
  }

  // ---- 2-way cross-wave reduction over wk (dedicated LDS, one barrier)
  if (wk == 1) {
#pragma unroll
    for (int nt = 0; nt < 4; ++nt) {
      const int q = 16 * nt + lb;
#pragma unroll
      for (int mtd = 0; mtd < 4; ++mtd)
        *(f32x4*)&red[wq][q][16 * mtd + 4 * G] = O[mtd][nt];
      if (G == 0) lred[wq * 64 + q] = lacc[nt];
    }
  }
  __syncthreads();
  if (wk == 0) {
    short* Ao = Ab + ((size_t)(n * SL + (qt << 7) + 64 * wq)) * EMB + h * HD;
#pragma unroll
    for (int nt = 0; nt < 4; ++nt) {
      const int q = 16 * nt + lb;
      const float inv = 1.f / (lacc[nt] + lred[wq * 64 + q]);
#pragma unroll
      for (int mtd = 0; mtd < 4; ++mtd) {
        const f32x4 t = *(const f32x4*)&red[wq][q][16 * mtd + 4 * G];
        const f32x4 s = t + O[mtd][nt];
        const short4 o = {f2b(s[0] * inv), f2b(s[1] * inv), f2b(s[2] * inv),
                          f2b(s[3] * inv)};
        *(short4*)(Ao + (size_t)q * EMB + 16 * mtd + 4 * G) = o;
      }
    }
  }
}

extern "C" void kernel_launch(void* const* d_in, const int* in_sizes, int n_in,
                              void* d_out, int out_size, void* d_ws, size_t ws_size,
                              hipStream_t stream) {
  const float* x  = (const float*)d_in[0];
  const float* Wq = (const float*)d_in[1];
  const float* Wk = (const float*)d_in[2];
  const float* Wv = (const float*)d_in[3];
  const float* Wo = (const float*)d_in[4];
  const float* bo = (const float*)d_in[5];
  float* out = (float*)d_out;

  // ws (bf16 elements): xb 4M | wqkv 3M | wob 1M | qb 4M | kb 4M | vt 4M = 40 MB
  short* xb   = (short*)d_ws;
  short* wqkv = xb + PROJ;
  short* wob  = wqkv + 3u * EMB * EMB;
  short* qb   = wob + (size_t)EMB * EMB;
  short* kb   = qb + PROJ;
  short* vt   = kb + PROJ;
  short* ab   = qb;  // alias: block-disjoint read-then-write regions

  cast_all<<<8192, 256, 0, stream>>>(x, Wq, Wk, Wv, Wo, xb, wqkv, wob);
  gemm_qkv<<<192, 512, 131072, stream>>>(xb, wqkv, qb, kb, vt);
  attn_mfma<<<dim3(NH, SL / 128, NB), 256, 0, stream>>>(qb, kb, vt, ab);
  gemm_out<<<dim3(16, 32), 256, 0, stream>>>(ab, wob, bo, out);
}